// Round 5
// baseline (438.401 us; speedup 1.0000x reference)
//
#include <hip/hip_runtime.h>
#include <hip/hip_bf16.h>

#define DFEAT 128

typedef short bf16x8 __attribute__((ext_vector_type(8)));
typedef float f32x4  __attribute__((ext_vector_type(4)));
typedef unsigned short u16x8 __attribute__((ext_vector_type(8)));

__device__ __forceinline__ unsigned bf16r(float f) {
    unsigned u = __float_as_uint(f);
    u += 0x7fffu + ((u >> 16) & 1u);   // round-to-nearest-even
    return u >> 16;
}
__device__ __forceinline__ unsigned pack_bf16(float lo, float hi) {
    return bf16r(lo) | (bf16r(hi) << 16);
}
__device__ __forceinline__ float blo(unsigned v) { return __uint_as_float(v << 16); }
__device__ __forceinline__ float bhi(unsigned v) { return __uint_as_float(v & 0xffff0000u); }

// ---------------- degree count (XCD-privatized, fire-and-forget atomics) ----------------
__global__ void deg_kernel(const int* __restrict__ ei, int* __restrict__ deg8, int E, int N) {
    int e = blockIdx.x * blockDim.x + threadIdx.x;
    if (e < E) {
        int r = ei[e];
        int c = ei[E + e];
        if (r != c) atomicAdd(&deg8[(blockIdx.x & 7) * N + r], 1);
    }
}

// ---------------- scan stage 1: sum deg8 -> dinv, poff, block-local inclusive scan ----------------
__global__ __launch_bounds__(1024) void scan1_kernel(const int* __restrict__ deg8,
                                                     int* __restrict__ poff,
                                                     int* __restrict__ row_ptr,
                                                     int* __restrict__ bsum,
                                                     float* __restrict__ dinv, int n) {
    __shared__ int wsums[16];
    int t = threadIdx.x;
    int idx = blockIdx.x * 1024 + t;
    int tot = 0;
    if (idx < n) {
        int run = 0;
        #pragma unroll
        for (int p = 0; p < 8; ++p) {
            int d = deg8[p * n + idx];
            poff[p * n + idx] = run;
            run += d;
        }
        tot = run;
        dinv[idx] = (tot > 0) ? rsqrtf((float)tot) : 0.f;
    }
    int vi = tot;
    #pragma unroll
    for (int off = 1; off < 64; off <<= 1) {
        int x = __shfl_up(vi, off);
        if ((t & 63) >= off) vi += x;
    }
    if ((t & 63) == 63) wsums[t >> 6] = vi;
    __syncthreads();
    if (t < 16) {
        int s = wsums[t];
        int si = s;
        #pragma unroll
        for (int off = 1; off < 16; off <<= 1) {
            int x = __shfl_up(si, off);
            if (t >= off) si += x;
        }
        wsums[t] = si - s;                  // exclusive prefix of wave sums
        if (t == 15) bsum[blockIdx.x] = si; // block total
    }
    __syncthreads();
    if (idx < n) row_ptr[idx + 1] = wsums[t >> 6] + vi;   // block-local inclusive
}

// ---------------- scan stage 2: exclusive scan of block sums (1 wave) ----------------
__global__ void scan2_kernel(int* __restrict__ bsum, int nb) {
    int t = threadIdx.x;   // 64 threads
    int carry = 0;
    for (int base = 0; base < nb; base += 64) {
        int v = (base + t < nb) ? bsum[base + t] : 0;
        int vi = v;
        #pragma unroll
        for (int off = 1; off < 64; off <<= 1) {
            int x = __shfl_up(vi, off);
            if (t >= off) vi += x;
        }
        if (base + t < nb) bsum[base + t] = carry + vi - v;  // exclusive
        carry += __shfl(vi, 63);
    }
}

// ---------------- scan stage 3: add block offsets ----------------
__global__ __launch_bounds__(1024) void scan3_kernel(int* __restrict__ row_ptr,
                                                     const int* __restrict__ bsum, int n) {
    int idx = blockIdx.x * 1024 + threadIdx.x;
    if (idx == 0) row_ptr[0] = 0;
    if (idx < n) row_ptr[idx + 1] += bsum[blockIdx.x];
}

// ---------------- CSR fill: packed (col:u16 | w:f16) ----------------
__global__ void fill_kernel(const int* __restrict__ ei, const int* __restrict__ row_ptr,
                            const int* __restrict__ poff, int* __restrict__ fillc8,
                            const float* __restrict__ dinv,
                            unsigned* __restrict__ e_cw, int E, int N) {
    int e = blockIdx.x * blockDim.x + threadIdx.x;
    if (e < E) {
        int r = ei[e];
        int c = ei[E + e];
        if (r != c) {
            int p = blockIdx.x & 7;
            int k = atomicAdd(&fillc8[p * N + r], 1);
            int pos = row_ptr[r] + poff[p * N + r] + k;
            float w = -dinv[r] * dinv[c];
            _Float16 hf = (_Float16)w;
            unsigned short wb;
            __builtin_memcpy(&wb, &hf, 2);
            e_cw[pos] = (unsigned)c | ((unsigned)wb << 16);
        }
    }
}

// ---------------- x (fp32) -> bf16x2-packed ----------------
__global__ void xconv_kernel(const float2* __restrict__ x, unsigned* __restrict__ xb, int n2) {
    int id = blockIdx.x * blockDim.x + threadIdx.x;
    if (id < n2) {
        float2 v = x[id];
        xb[id] = pack_bf16(v.x, v.y);
    }
}

// ---------------- W1/2/3 [3][128][128] fp32 -> Wt [layer][seg][n][k] bf16 ----------------
__global__ void wprep_kernel(const float* __restrict__ W1, const float* __restrict__ W2,
                             const float* __restrict__ W3, unsigned short* __restrict__ Wt) {
    int id = blockIdx.x * blockDim.x + threadIdx.x;
    const int PER = 3 * DFEAT * DFEAT;
    if (id < 3 * PER) {
        int layer = id / PER;
        int rem = id - layer * PER;
        const float* W = (layer == 0) ? W1 : ((layer == 1) ? W2 : W3);
        int seg = rem >> 14;
        int k   = (rem >> 7) & 127;
        int nn  = rem & 127;
        Wt[layer * PER + (seg << 14) + (nn << 7) + k] = (unsigned short)bf16r(W[rem]);
    }
}

// ---------------- sparse prop (bf16 in/out, fp32 accumulate) ----------------
// 4 nodes per wave: lane = (q = node slot [0,4), s = 16B feature segment [0,16)).
// Each global_load_dwordx4 gathers 4 edges (1 KB); unroll 6 -> 6 KB in flight
// per wave. Lane owns features [8s, 8s+8) of node q -> no cross-lane reduce.
__global__ __launch_bounds__(256) void prop_bf16_kernel(
    const uint4* __restrict__ hin4, const uint4* __restrict__ sub4,
    uint4* __restrict__ hout4,
    const int* __restrict__ row_ptr, const unsigned* __restrict__ e_cw,
    float alpha, int n)
{
    const int t = threadIdx.x;
    const int lane = t & 63;
    const int q = lane >> 4;       // node slot within wave
    const int s = lane & 15;       // 16B segment (features 8s..8s+7)
    int node = blockIdx.x * 16 + (t >> 6) * 4 + q;
    int nodec = node < n ? node : n - 1;
    int rs = row_ptr[nodec];
    int deg = row_ptr[nodec + 1] - rs;
    if (node >= n) deg = 0;
    int m = deg;
    m = max(m, __shfl_xor(m, 16));
    m = max(m, __shfl_xor(m, 32));   // wave-uniform max degree over the 4 slots

    float acc[8];
    #pragma unroll
    for (int i = 0; i < 8; ++i) acc[i] = 0.f;

    for (int i0 = 0; i0 < m; i0 += 6) {
        uint4 vv[6]; float wv[6];
        #pragma unroll
        for (int u = 0; u < 6; ++u) {
            int i = i0 + u;
            unsigned cw = (i < deg) ? e_cw[rs + i] : 0u;   // masked slot: col 0, w 0
            unsigned short wb = (unsigned short)(cw >> 16);
            _Float16 hf; __builtin_memcpy(&hf, &wb, 2);
            wv[u] = (float)hf;
            vv[u] = hin4[(size_t)(cw & 0xffffu) * 16 + s];
        }
        #pragma unroll
        for (int u = 0; u < 6; ++u) {
            float w = wv[u];
            acc[0] += w * blo(vv[u].x);  acc[1] += w * bhi(vv[u].x);
            acc[2] += w * blo(vv[u].y);  acc[3] += w * bhi(vv[u].y);
            acc[4] += w * blo(vv[u].z);  acc[5] += w * bhi(vv[u].z);
            acc[6] += w * blo(vv[u].w);  acc[7] += w * bhi(vv[u].w);
        }
    }
    #pragma unroll
    for (int i = 0; i < 8; ++i) acc[i] *= alpha;
    size_t rowoff = (size_t)nodec * 16 + s;
    if (sub4) {
        uint4 sv = sub4[rowoff];
        acc[0] -= blo(sv.x);  acc[1] -= bhi(sv.x);
        acc[2] -= blo(sv.y);  acc[3] -= bhi(sv.y);
        acc[4] -= blo(sv.z);  acc[5] -= bhi(sv.z);
        acc[6] -= blo(sv.w);  acc[7] -= bhi(sv.w);
    }
    if (node < n) {
        uint4 o;
        o.x = pack_bf16(acc[0], acc[1]);
        o.y = pack_bf16(acc[2], acc[3]);
        o.z = pack_bf16(acc[4], acc[5]);
        o.w = pack_bf16(acc[6], acc[7]);
        hout4[rowoff] = o;
    }
}

// ---------------- fused 3-way MFMA GEMM + bias + ReLU ----------------
#define WPAD 136
__global__ __launch_bounds__(256) void gemm3_mfma_kernel(
    const unsigned short* __restrict__ X0, const unsigned short* __restrict__ X1,
    const unsigned short* __restrict__ X2,
    const unsigned short* __restrict__ Wt, const float* __restrict__ bias,
    void* __restrict__ out, int n, int out_bf16)
{
    __shared__ unsigned short Ws[DFEAT * WPAD];   // 34816 B
    const int t    = threadIdx.x;
    const int wave = t >> 6;
    const int lane = t & 63;
    const int quad = lane >> 4;
    const int l16  = lane & 15;

    const int row_base = blockIdx.x * 128 + wave * 32;
    int r0 = row_base + l16;       if (r0 >= n) r0 = n - 1;
    int r1 = row_base + 16 + l16;  if (r1 >= n) r1 = n - 1;

    const unsigned short* Xps[3] = {X0, X1, X2};

    f32x4 acc[2][8];
    #pragma unroll
    for (int tt = 0; tt < 2; ++tt)
        #pragma unroll
        for (int c = 0; c < 8; ++c) acc[tt][c] = (f32x4){0.f, 0.f, 0.f, 0.f};

    const int srow = t >> 1;            // staging: row 0..127
    const int shalf = (t & 1) * 64;     // half-row

    #pragma unroll
    for (int seg = 0; seg < 3; ++seg) {
        __syncthreads();   // previous seg fully consumed
        const unsigned short* Wp = Wt + (seg << 14);
        #pragma unroll
        for (int i = 0; i < 8; ++i) {
            *(u16x8*)&Ws[srow * WPAD + shalf + i * 8] =
                *(const u16x8*)&Wp[srow * DFEAT + shalf + i * 8];
        }
        __syncthreads();
        const unsigned short* A0 = Xps[seg] + (size_t)r0 * DFEAT;
        const unsigned short* A1 = Xps[seg] + (size_t)r1 * DFEAT;
        #pragma unroll
        for (int kk = 0; kk < 4; ++kk) {
            const int ko = kk * 32 + quad * 8;
            bf16x8 a0 = *(const bf16x8*)(A0 + ko);
            bf16x8 a1 = *(const bf16x8*)(A1 + ko);
            #pragma unroll
            for (int c = 0; c < 8; ++c) {
                bf16x8 b = *(const bf16x8*)&Ws[(c * 16 + l16) * WPAD + ko];
                acc[0][c] = __builtin_amdgcn_mfma_f32_16x16x32_bf16(a0, b, acc[0][c], 0, 0, 0);
                acc[1][c] = __builtin_amdgcn_mfma_f32_16x16x32_bf16(a1, b, acc[1][c], 0, 0, 0);
            }
        }
    }

    // C/D layout: col = lane&15, row = quad*4 + reg
    #pragma unroll
    for (int tt = 0; tt < 2; ++tt) {
        int orow0 = blockIdx.x * 128 + wave * 32 + tt * 16 + quad * 4;
        #pragma unroll
        for (int c = 0; c < 8; ++c) {
            int col = c * 16 + l16;
            float bv = bias[col];
            #pragma unroll
            for (int r = 0; r < 4; ++r) {
                int orow = orow0 + r;
                if (orow < n) {
                    float v = fmaxf(acc[tt][c][r] + bv, 0.f);
                    if (out_bf16)
                        ((unsigned short*)out)[(size_t)orow * DFEAT + col] = (unsigned short)bf16r(v);
                    else
                        ((float*)out)[(size_t)orow * DFEAT + col] = v;
                }
            }
        }
    }
}

extern "C" void kernel_launch(void* const* d_in, const int* in_sizes, int n_in,
                              void* d_out, int out_size, void* d_ws, size_t ws_size,
                              hipStream_t stream) {
    const float* x  = (const float*)d_in[0];
    const int*   ei = (const int*)d_in[1];
    const float* W1 = (const float*)d_in[2];
    const float* b1 = (const float*)d_in[3];
    const float* W2 = (const float*)d_in[4];
    const float* b2 = (const float*)d_in[5];
    const float* W3 = (const float*)d_in[6];
    const float* b3 = (const float*)d_in[7];

    const int N = in_sizes[0] / DFEAT;   // 50000
    const int E = in_sizes[1] / 2;       // 800000
    const int NPK = N * (DFEAT / 2);     // packed bf16x2 words per array
    const int NB = (N + 1023) / 1024;    // scan blocks

    // workspace layout
    unsigned* xb  = (unsigned*)d_ws;
    unsigned* t1b = xb  + NPK;
    unsigned* t2b = t1b + NPK;
    unsigned* ab  = t2b + NPK;
    unsigned short* wt = (unsigned short*)(ab + NPK);   // 3 layers * 3*128*128
    int*   deg8    = (int*)(wt + 3 * 3 * DFEAT * DFEAT);
    int*   poff    = deg8 + 8 * N;
    int*   fillc8  = poff + 8 * N;
    int*   row_ptr = fillc8 + 8 * N;
    float* dinv    = (float*)(row_ptr + (N + 1));
    unsigned* e_cw = (unsigned*)(dinv + N);
    int*   bsum    = (int*)(e_cw + E);

    hipMemsetAsync(deg8,   0, sizeof(int) * 8 * N, stream);
    hipMemsetAsync(fillc8, 0, sizeof(int) * 8 * N, stream);

    deg_kernel<<<(E + 255) / 256, 256, 0, stream>>>(ei, deg8, E, N);
    scan1_kernel<<<NB, 1024, 0, stream>>>(deg8, poff, row_ptr, bsum, dinv, N);
    scan2_kernel<<<1, 64, 0, stream>>>(bsum, NB);
    scan3_kernel<<<NB, 1024, 0, stream>>>(row_ptr, bsum, N);
    fill_kernel<<<(E + 255) / 256, 256, 0, stream>>>(ei, row_ptr, poff, fillc8, dinv, e_cw, E, N);

    xconv_kernel<<<(NPK + 255) / 256, 256, 0, stream>>>((const float2*)x, xb, NPK);
    const int WELEM = 3 * DFEAT * DFEAT;
    wprep_kernel<<<(3 * WELEM + 255) / 256, 256, 0, stream>>>(W1, W2, W3, wt);

    const float* bl[3] = {b1, b2, b3};
    const unsigned* hin = xb;
    const int prop_grid = (N + 15) / 16;
    const int gemm_grid = (N + 127) / 128;
    for (int l = 0; l < 3; ++l) {
        // Tx1 = L_hat @ h
        prop_bf16_kernel<<<prop_grid, 256, 0, stream>>>(
            (const uint4*)hin, nullptr, (uint4*)t1b, row_ptr, e_cw, 1.f, N);
        // Tx2 = 2 * L_hat @ Tx1 - h
        prop_bf16_kernel<<<prop_grid, 256, 0, stream>>>(
            (const uint4*)t1b, (const uint4*)hin, (uint4*)t2b, row_ptr, e_cw, 2.f, N);
        // out = relu(h@W0 + Tx1@W1 + Tx2@W2 + b)
        void* hout = (l == 2) ? d_out : (void*)ab;
        gemm3_mfma_kernel<<<gemm_grid, 256, 0, stream>>>(
            (const unsigned short*)hin, (const unsigned short*)t1b, (const unsigned short*)t2b,
            wt + l * WELEM, bl[l], hout, N, (l == 2) ? 0 : 1);
        hin = ab;
    }
}

// Round 6
// 404.875 us; speedup vs baseline: 1.0828x; 1.0828x over previous
//
#include <hip/hip_runtime.h>
#include <hip/hip_bf16.h>

#define DFEAT 128

typedef short bf16x8 __attribute__((ext_vector_type(8)));
typedef float f32x4  __attribute__((ext_vector_type(4)));
typedef unsigned short u16x8 __attribute__((ext_vector_type(8)));

__device__ __forceinline__ unsigned bf16r(float f) {
    unsigned u = __float_as_uint(f);
    u += 0x7fffu + ((u >> 16) & 1u);   // round-to-nearest-even
    return u >> 16;
}
__device__ __forceinline__ unsigned pack_bf16(float lo, float hi) {
    return bf16r(lo) | (bf16r(hi) << 16);
}

// ---------------- degree count (XCD-privatized, fire-and-forget atomics) ----------------
__global__ void deg_kernel(const int* __restrict__ ei, int* __restrict__ deg8, int E, int N) {
    int e = blockIdx.x * blockDim.x + threadIdx.x;
    if (e < E) {
        int r = ei[e];
        int c = ei[E + e];
        if (r != c) atomicAdd(&deg8[(blockIdx.x & 7) * N + r], 1);
    }
}

// ---------------- scan stage 1: sum deg8 -> dinv, poff, block-local inclusive scan ----------------
__global__ __launch_bounds__(1024) void scan1_kernel(const int* __restrict__ deg8,
                                                     int* __restrict__ poff,
                                                     int* __restrict__ row_ptr,
                                                     int* __restrict__ bsum,
                                                     float* __restrict__ dinv, int n) {
    __shared__ int wsums[16];
    int t = threadIdx.x;
    int idx = blockIdx.x * 1024 + t;
    int tot = 0;
    if (idx < n) {
        int run = 0;
        #pragma unroll
        for (int p = 0; p < 8; ++p) {
            int d = deg8[p * n + idx];
            poff[p * n + idx] = run;
            run += d;
        }
        tot = run;
        dinv[idx] = (tot > 0) ? rsqrtf((float)tot) : 0.f;
    }
    int vi = tot;
    #pragma unroll
    for (int off = 1; off < 64; off <<= 1) {
        int x = __shfl_up(vi, off);
        if ((t & 63) >= off) vi += x;
    }
    if ((t & 63) == 63) wsums[t >> 6] = vi;
    __syncthreads();
    if (t < 16) {
        int s = wsums[t];
        int si = s;
        #pragma unroll
        for (int off = 1; off < 16; off <<= 1) {
            int x = __shfl_up(si, off);
            if (t >= off) si += x;
        }
        wsums[t] = si - s;                  // exclusive prefix of wave sums
        if (t == 15) bsum[blockIdx.x] = si; // block total
    }
    __syncthreads();
    if (idx < n) row_ptr[idx + 1] = wsums[t >> 6] + vi;   // block-local inclusive
}

// ---------------- scan stage 2: exclusive scan of block sums (1 wave) ----------------
__global__ void scan2_kernel(int* __restrict__ bsum, int nb) {
    int t = threadIdx.x;   // 64 threads
    int carry = 0;
    for (int base = 0; base < nb; base += 64) {
        int v = (base + t < nb) ? bsum[base + t] : 0;
        int vi = v;
        #pragma unroll
        for (int off = 1; off < 64; off <<= 1) {
            int x = __shfl_up(vi, off);
            if (t >= off) vi += x;
        }
        if (base + t < nb) bsum[base + t] = carry + vi - v;  // exclusive
        carry += __shfl(vi, 63);
    }
}

// ---------------- scan stage 3: add block offsets ----------------
__global__ __launch_bounds__(1024) void scan3_kernel(int* __restrict__ row_ptr,
                                                     const int* __restrict__ bsum, int n) {
    int idx = blockIdx.x * 1024 + threadIdx.x;
    if (idx == 0) row_ptr[0] = 0;
    if (idx < n) row_ptr[idx + 1] += bsum[blockIdx.x];
}

// ---------------- CSR fill: packed (col:u16 | w:f16) ----------------
__global__ void fill_kernel(const int* __restrict__ ei, const int* __restrict__ row_ptr,
                            const int* __restrict__ poff, int* __restrict__ fillc8,
                            const float* __restrict__ dinv,
                            unsigned* __restrict__ e_cw, int E, int N) {
    int e = blockIdx.x * blockDim.x + threadIdx.x;
    if (e < E) {
        int r = ei[e];
        int c = ei[E + e];
        if (r != c) {
            int p = blockIdx.x & 7;
            int k = atomicAdd(&fillc8[p * N + r], 1);
            int pos = row_ptr[r] + poff[p * N + r] + k;
            float w = -dinv[r] * dinv[c];
            _Float16 hf = (_Float16)w;
            unsigned short wb;
            __builtin_memcpy(&wb, &hf, 2);
            e_cw[pos] = (unsigned)c | ((unsigned)wb << 16);
        }
    }
}

// ---------------- fused convert: x->bf16 pack + W1/2/3 -> transposed bf16 ----------------
__global__ void conv_kernel(const float2* __restrict__ x, unsigned* __restrict__ xb, int npk,
                            const float* __restrict__ W1, const float* __restrict__ W2,
                            const float* __restrict__ W3, unsigned short* __restrict__ Wt) {
    int id = blockIdx.x * blockDim.x + threadIdx.x;
    if (id < npk) {
        float2 v = x[id];
        xb[id] = pack_bf16(v.x, v.y);
        return;
    }
    int id2 = id - npk;
    const int PER = 3 * DFEAT * DFEAT;
    if (id2 < 3 * PER) {
        int layer = id2 / PER;
        int rem = id2 - layer * PER;
        const float* W = (layer == 0) ? W1 : ((layer == 1) ? W2 : W3);
        int seg = rem >> 14;
        int k   = (rem >> 7) & 127;
        int nn  = rem & 127;
        Wt[layer * PER + (seg << 14) + (nn << 7) + k] = (unsigned short)bf16r(W[rem]);
    }
}

// ---------------- sparse prop (bf16 in/out, fp32 accumulate) ----------------
// 1 wave per node (wave-uniform node -> scalar metadata loads); 16-wide
// load-then-FMA phases for 16 outstanding gathers per wave.
__global__ __launch_bounds__(256) void prop_bf16_kernel(
    const unsigned* __restrict__ hin, const unsigned* __restrict__ sub,
    unsigned* __restrict__ hout,
    const int* __restrict__ row_ptr, const unsigned* __restrict__ e_cw,
    float alpha, int n)
{
    int wv = __builtin_amdgcn_readfirstlane(threadIdx.x >> 6);
    int node = blockIdx.x * 4 + wv;
    int t = threadIdx.x & 63;     // feature pair: features 2t, 2t+1
    if (node >= n) return;
    int s = row_ptr[node];
    int e = row_ptr[node + 1];
    float a0 = 0.f, a1 = 0.f;
    int j = s;
    for (; j + 16 <= e; j += 16) {
        unsigned cw[16];
        #pragma unroll
        for (int q = 0; q < 16; ++q) cw[q] = e_cw[j + q];
        unsigned v[16];
        #pragma unroll
        for (int q = 0; q < 16; ++q)
            v[q] = hin[(size_t)(cw[q] & 0xffffu) * 64 + t];
        #pragma unroll
        for (int q = 0; q < 16; ++q) {
            unsigned short wb = (unsigned short)(cw[q] >> 16);
            _Float16 hf; __builtin_memcpy(&hf, &wb, 2);
            float w = (float)hf;
            a0 += w * __uint_as_float(v[q] << 16);
            a1 += w * __uint_as_float(v[q] & 0xffff0000u);
        }
    }
    for (; j + 4 <= e; j += 4) {
        unsigned cw[4];
        #pragma unroll
        for (int q = 0; q < 4; ++q) cw[q] = e_cw[j + q];
        unsigned v[4];
        #pragma unroll
        for (int q = 0; q < 4; ++q)
            v[q] = hin[(size_t)(cw[q] & 0xffffu) * 64 + t];
        #pragma unroll
        for (int q = 0; q < 4; ++q) {
            unsigned short wb = (unsigned short)(cw[q] >> 16);
            _Float16 hf; __builtin_memcpy(&hf, &wb, 2);
            float w = (float)hf;
            a0 += w * __uint_as_float(v[q] << 16);
            a1 += w * __uint_as_float(v[q] & 0xffff0000u);
        }
    }
    for (; j < e; ++j) {
        unsigned cwv = e_cw[j];
        unsigned short wb = (unsigned short)(cwv >> 16);
        _Float16 hf; __builtin_memcpy(&hf, &wb, 2);
        float w = (float)hf;
        unsigned v = hin[(size_t)(cwv & 0xffffu) * 64 + t];
        a0 += w * __uint_as_float(v << 16);
        a1 += w * __uint_as_float(v & 0xffff0000u);
    }
    a0 *= alpha; a1 *= alpha;
    if (sub) {
        unsigned v = sub[(size_t)node * 64 + t];
        a0 -= __uint_as_float(v << 16);
        a1 -= __uint_as_float(v & 0xffff0000u);
    }
    hout[(size_t)node * 64 + t] = pack_bf16(a0, a1);
}

// ---------------- fused 3-way MFMA GEMM + bias + ReLU ----------------
#define WPAD 136
__global__ __launch_bounds__(256) void gemm3_mfma_kernel(
    const unsigned short* __restrict__ X0, const unsigned short* __restrict__ X1,
    const unsigned short* __restrict__ X2,
    const unsigned short* __restrict__ Wt, const float* __restrict__ bias,
    void* __restrict__ out, int n, int out_bf16)
{
    __shared__ unsigned short Ws[DFEAT * WPAD];   // 34816 B
    const int t    = threadIdx.x;
    const int wave = t >> 6;
    const int lane = t & 63;
    const int quad = lane >> 4;
    const int l16  = lane & 15;

    const int row_base = blockIdx.x * 128 + wave * 32;
    int r0 = row_base + l16;       if (r0 >= n) r0 = n - 1;
    int r1 = row_base + 16 + l16;  if (r1 >= n) r1 = n - 1;

    const unsigned short* Xps[3] = {X0, X1, X2};

    f32x4 acc[2][8];
    #pragma unroll
    for (int tt = 0; tt < 2; ++tt)
        #pragma unroll
        for (int c = 0; c < 8; ++c) acc[tt][c] = (f32x4){0.f, 0.f, 0.f, 0.f};

    const int srow = t >> 1;            // staging: row 0..127
    const int shalf = (t & 1) * 64;     // half-row

    #pragma unroll
    for (int seg = 0; seg < 3; ++seg) {
        __syncthreads();   // previous seg fully consumed
        const unsigned short* Wp = Wt + (seg << 14);
        #pragma unroll
        for (int i = 0; i < 8; ++i) {
            *(u16x8*)&Ws[srow * WPAD + shalf + i * 8] =
                *(const u16x8*)&Wp[srow * DFEAT + shalf + i * 8];
        }
        __syncthreads();
        const unsigned short* A0 = Xps[seg] + (size_t)r0 * DFEAT;
        const unsigned short* A1 = Xps[seg] + (size_t)r1 * DFEAT;
        #pragma unroll
        for (int kk = 0; kk < 4; ++kk) {
            const int ko = kk * 32 + quad * 8;
            bf16x8 a0 = *(const bf16x8*)(A0 + ko);
            bf16x8 a1 = *(const bf16x8*)(A1 + ko);
            #pragma unroll
            for (int c = 0; c < 8; ++c) {
                bf16x8 b = *(const bf16x8*)&Ws[(c * 16 + l16) * WPAD + ko];
                acc[0][c] = __builtin_amdgcn_mfma_f32_16x16x32_bf16(a0, b, acc[0][c], 0, 0, 0);
                acc[1][c] = __builtin_amdgcn_mfma_f32_16x16x32_bf16(a1, b, acc[1][c], 0, 0, 0);
            }
        }
    }

    // C/D layout: col = lane&15, row = quad*4 + reg
    #pragma unroll
    for (int tt = 0; tt < 2; ++tt) {
        int orow0 = blockIdx.x * 128 + wave * 32 + tt * 16 + quad * 4;
        #pragma unroll
        for (int c = 0; c < 8; ++c) {
            int col = c * 16 + l16;
            float bv = bias[col];
            #pragma unroll
            for (int r = 0; r < 4; ++r) {
                int orow = orow0 + r;
                if (orow < n) {
                    float v = fmaxf(acc[tt][c][r] + bv, 0.f);
                    if (out_bf16)
                        ((unsigned short*)out)[(size_t)orow * DFEAT + col] = (unsigned short)bf16r(v);
                    else
                        ((float*)out)[(size_t)orow * DFEAT + col] = v;
                }
            }
        }
    }
}

extern "C" void kernel_launch(void* const* d_in, const int* in_sizes, int n_in,
                              void* d_out, int out_size, void* d_ws, size_t ws_size,
                              hipStream_t stream) {
    const float* x  = (const float*)d_in[0];
    const int*   ei = (const int*)d_in[1];
    const float* W1 = (const float*)d_in[2];
    const float* b1 = (const float*)d_in[3];
    const float* W2 = (const float*)d_in[4];
    const float* b2 = (const float*)d_in[5];
    const float* W3 = (const float*)d_in[6];
    const float* b3 = (const float*)d_in[7];

    const int N = in_sizes[0] / DFEAT;   // 50000
    const int E = in_sizes[1] / 2;       // 800000
    const int NPK = N * (DFEAT / 2);     // packed bf16x2 words per array
    const int NB = (N + 1023) / 1024;    // scan blocks

    // workspace layout (deg8 and fillc8 adjacent -> one memset)
    unsigned* xb  = (unsigned*)d_ws;
    unsigned* t1b = xb  + NPK;
    unsigned* t2b = t1b + NPK;
    unsigned* ab  = t2b + NPK;
    unsigned short* wt = (unsigned short*)(ab + NPK);   // 3 layers * 3*128*128
    int*   deg8    = (int*)(wt + 3 * 3 * DFEAT * DFEAT);
    int*   fillc8  = deg8 + 8 * N;
    int*   poff    = fillc8 + 8 * N;
    int*   row_ptr = poff + 8 * N;
    float* dinv    = (float*)(row_ptr + (N + 1));
    unsigned* e_cw = (unsigned*)(dinv + N);
    int*   bsum    = (int*)(e_cw + E);

    hipMemsetAsync(deg8, 0, sizeof(int) * 16 * N, stream);   // deg8 + fillc8

    deg_kernel<<<(E + 255) / 256, 256, 0, stream>>>(ei, deg8, E, N);
    scan1_kernel<<<NB, 1024, 0, stream>>>(deg8, poff, row_ptr, bsum, dinv, N);
    scan2_kernel<<<1, 64, 0, stream>>>(bsum, NB);
    scan3_kernel<<<NB, 1024, 0, stream>>>(row_ptr, bsum, N);
    fill_kernel<<<(E + 255) / 256, 256, 0, stream>>>(ei, row_ptr, poff, fillc8, dinv, e_cw, E, N);

    const int WELEM = 3 * DFEAT * DFEAT;
    const int CONVT = NPK + 3 * WELEM;
    conv_kernel<<<(CONVT + 255) / 256, 256, 0, stream>>>(
        (const float2*)x, xb, NPK, W1, W2, W3, wt);

    const float* bl[3] = {b1, b2, b3};
    const unsigned* hin = xb;
    const int prop_grid = (N + 3) / 4;
    const int gemm_grid = (N + 127) / 128;
    for (int l = 0; l < 3; ++l) {
        // Tx1 = L_hat @ h
        prop_bf16_kernel<<<prop_grid, 256, 0, stream>>>(hin, nullptr, t1b, row_ptr, e_cw, 1.f, N);
        // Tx2 = 2 * L_hat @ Tx1 - h
        prop_bf16_kernel<<<prop_grid, 256, 0, stream>>>(t1b, hin, t2b, row_ptr, e_cw, 2.f, N);
        // out = relu(h@W0 + Tx1@W1 + Tx2@W2 + b)
        void* hout = (l == 2) ? d_out : (void*)ab;
        gemm3_mfma_kernel<<<gemm_grid, 256, 0, stream>>>(
            (const unsigned short*)hin, (const unsigned short*)t1b, (const unsigned short*)t2b,
            wt + l * WELEM, bl[l], hout, N, (l == 2) ? 0 : 1);
        hin = ab;
    }
}